// Round 6
// baseline (253.413 us; speedup 1.0000x reference)
//
#include <hip/hip_runtime.h>
#include <hip/hip_bf16.h>

#define BATCH 4
#define SEQ   4096
#define DIN   512
#define DOUT  64

typedef __attribute__((ext_vector_type(4))) float f32x4;
typedef __attribute__((ext_vector_type(8))) short bf16x8;   // 8 bf16 = 4 VGPRs
typedef __attribute__((ext_vector_type(4))) short bf16x4;   // 4 bf16 = 2 VGPRs

__device__ __forceinline__ f32x4 mfma16(bf16x8 a, bf16x8 b, f32x4 c) {
    return __builtin_amdgcn_mfma_f32_16x16x32_bf16(a, b, c, 0, 0, 0);
}
// K=16 variant: A[m][k]: m=lane&15, k=quad*4+j ; B[k][n]: n=lane&15, k=quad*4+j
__device__ __forceinline__ f32x4 mfma16k(bf16x4 a, bf16x4 b, f32x4 c) {
    return __builtin_amdgcn_mfma_f32_16x16x16bf16_1k(a, b, c, 0, 0, 0);
}

// fp32 -> bf16 round-to-nearest-even (finite inputs only)
__device__ __forceinline__ short f2bf(float f) {
    union { float f; unsigned u; } x; x.f = f;
    unsigned r = x.u + 0x7FFFu + ((x.u >> 16) & 1u);
    return (short)(r >> 16);
}

// pack two fp32 into bf16x2 (truncation) in ONE v_perm_b32
__device__ __forceinline__ unsigned pack_bf2(float lo, float hi) {
    union { float f; unsigned u; } a, b; a.f = lo; b.f = hi;
    return __builtin_amdgcn_perm(b.u, a.u, 0x07060302u);
}

// Q pre-scale: 1/sqrt(64) * log2(e)  (softmax done in base 2)
#define QSCALE 0.1803368801111204f

// ---------------------------------------------------------------------------
// W convert+transpose: W[512][64] fp32 -> Wt[64][512] bf16 (coalesced reads).
// ---------------------------------------------------------------------------
__global__ __launch_bounds__(256) void wconv_kernel(
    const float* __restrict__ Wq, const float* __restrict__ Wk,
    const float* __restrict__ Wv, short* __restrict__ Wt)
{
    const int m = blockIdx.y;
    const float* W = (m == 0) ? Wq : (m == 1) ? Wk : Wv;
    const int idx = blockIdx.x * 256 + threadIdx.x;   // 0..32767
    const int k = idx >> 6;
    const int n = idx & 63;
    Wt[m * (DOUT * DIN) + n * DIN + k] = f2bf(W[idx]);
}

// ---------------------------------------------------------------------------
// QKV projection, bf16 MFMA, software-pipelined loads.
// sched_barrier(0) after the prefetch group: R3-R5 evidence shows the machine
// scheduler sinks prefetch loads to their uses (VGPR crushed to 36-72),
// serializing the loop into ~6 L2 round-trips/iter. The barrier pins the
// loads above the MFMAs -> values live across -> all loads in flight at once.
// m<2 : C = X·W  -> Qb/Kb row-major (Q pre-scaled by QSCALE)
// m==2: C = Wt·X^T (swapped operands) -> Vt[e][s], 32B-contiguous stores.
// ---------------------------------------------------------------------------
__global__ __launch_bounds__(256) __attribute__((amdgpu_waves_per_eu(2, 4)))
void proj_kernel(
    const float* __restrict__ Xq, const float* __restrict__ Xk, const float* __restrict__ Xv,
    const short* __restrict__ Wt,
    short* __restrict__ Qb, short* __restrict__ Kb, short* __restrict__ Vt)
{
    const int m = blockIdx.y;
    const float* X  = (m == 0) ? Xq : (m == 1) ? Xk : Xv;
    const short* Wm = Wt + m * (DOUT * DIN);

    const int tid  = threadIdx.x;
    const int wv   = tid >> 6;
    const int lane = tid & 63;
    const int quad = lane >> 4;
    const int l16  = lane & 15;
    const long row0 = (long)blockIdx.x * 64 + wv * 16;

    f32x4 acc[4];
    #pragma unroll
    for (int e = 0; e < 4; ++e) acc[e] = (f32x4){0.f, 0.f, 0.f, 0.f};

    const float* xp = X + (row0 + l16) * DIN + quad * 8;
    const short* wp = Wm + l16 * DIN + quad * 8;    // e-tile stride = 16*DIN

    // prologue: preload iter 0
    float4 cxa = *(const float4*)(xp);
    float4 cxb = *(const float4*)(xp + 4);
    bf16x8 cw0 = *(const bf16x8*)(wp);
    bf16x8 cw1 = *(const bf16x8*)(wp + 16 * DIN);
    bf16x8 cw2 = *(const bf16x8*)(wp + 32 * DIN);
    bf16x8 cw3 = *(const bf16x8*)(wp + 48 * DIN);

    #pragma unroll 4
    for (int k0 = 0; k0 < DIN; k0 += 32) {
        const int kn = (k0 + 32 < DIN) ? (k0 + 32) : 0;   // last prefetch is dead
        float4 nxa = *(const float4*)(xp + kn);
        float4 nxb = *(const float4*)(xp + kn + 4);
        bf16x8 nw0 = *(const bf16x8*)(wp + kn);
        bf16x8 nw1 = *(const bf16x8*)(wp + kn + 16 * DIN);
        bf16x8 nw2 = *(const bf16x8*)(wp + kn + 32 * DIN);
        bf16x8 nw3 = *(const bf16x8*)(wp + kn + 48 * DIN);
        __builtin_amdgcn_sched_barrier(0);   // pin prefetch above compute

        bf16x8 af;
        af[0] = f2bf(cxa.x); af[1] = f2bf(cxa.y); af[2] = f2bf(cxa.z); af[3] = f2bf(cxa.w);
        af[4] = f2bf(cxb.x); af[5] = f2bf(cxb.y); af[6] = f2bf(cxb.z); af[7] = f2bf(cxb.w);

        if (m < 2) {
            acc[0] = mfma16(af, cw0, acc[0]);
            acc[1] = mfma16(af, cw1, acc[1]);
            acc[2] = mfma16(af, cw2, acc[2]);
            acc[3] = mfma16(af, cw3, acc[3]);
        } else {
            acc[0] = mfma16(cw0, af, acc[0]);
            acc[1] = mfma16(cw1, af, acc[1]);
            acc[2] = mfma16(cw2, af, acc[2]);
            acc[3] = mfma16(cw3, af, acc[3]);
        }
        cxa = nxa; cxb = nxb;
        cw0 = nw0; cw1 = nw1; cw2 = nw2; cw3 = nw3;
    }

    if (m < 2) {
        short* O = (m == 0) ? Qb : Kb;
        const float sc = (m == 0) ? QSCALE : 1.0f;
        #pragma unroll
        for (int e = 0; e < 4; ++e)
            #pragma unroll
            for (int r = 0; r < 4; ++r)
                O[(row0 + quad * 4 + r) * DOUT + e * 16 + l16] = f2bf(acc[e][r] * sc);
    } else {
        const long b = row0 >> 12;
        const long s = row0 & (SEQ - 1);
        #pragma unroll
        for (int e = 0; e < 4; ++e)
            #pragma unroll
            for (int r = 0; r < 4; ++r)
                Vt[(b * DOUT + e * 16 + quad * 4 + r) * SEQ + s + l16] = f2bf(acc[e][r]);
    }
}

// ---------------------------------------------------------------------------
// Causal flash attention, transposed domain (scores^T = K·Q^T), 64 keys/iter.
// sched_barrier(0) after each prefetch group (see proj comment / R5
// post-mortem): forces all 24 K/V prefetch loads into flight concurrently
// instead of 6-8 serial L2 round-trips per iteration.
// 1D grid, XCD swizzle: batch b on XCDs {2b,2b+1} (FETCH 17.3->5.2 MB, R5).
// Per lane: q = l16; keys = kh*16 + quad*4 + r. Softmax in-register +
// 4 shuffles per 64 keys. PV via 16x16x16 MFMA: score C-layout == P B-layout,
// no cross-lane P movement. O accumulated as O^T.
// ---------------------------------------------------------------------------
__global__ __launch_bounds__(256) __attribute__((amdgpu_waves_per_eu(2, 3)))
void flash_kernel(
    const short* __restrict__ Qb, const short* __restrict__ Kb,
    const short* __restrict__ Vt, float* __restrict__ Out)
{
    __shared__ float s_m[4][16];
    __shared__ float s_l[4][16];
    __shared__ float s_acc[4][16][65];

    const int i    = blockIdx.x;
    const int b    = (i & 7) >> 1;                       // batch -> XCD pair
    const int qt   = 255 - (((i >> 3) << 1) | (i & 1));  // heavy tiles first
    const int tid  = threadIdx.x;
    const int wv   = tid >> 6;
    const int lane = tid & 63;
    const int quad = lane >> 4;
    const int l16  = lane & 15;
    const int q0   = qt * 16;

    // Q as B-frag: B[k=d][n=q]
    const short* Qp = Qb + ((long)b * SEQ + q0 + l16) * DOUT + quad * 8;
    bf16x8 qf0 = *(const bf16x8*)(Qp);        // d = 0..31
    bf16x8 qf1 = *(const bf16x8*)(Qp + 32);   // d = 32..63

    const short* Kbase = Kb + (long)b * SEQ * DOUT;
    const short* Vbase = Vt + (long)b * DOUT * SEQ;

    f32x4 acc[4];   // O^T tiles: row = e-offset (quad*4+r), col = q (l16)
    #pragma unroll
    for (int e = 0; e < 4; ++e) acc[e] = (f32x4){0.f, 0.f, 0.f, 0.f};
    float mrow = -1e30f, lrow = 0.f;

    const int q_hi = q0 + 15;
    const int qg   = q0 + l16;

    // per-lane V row pointers (et = 0..3)
    const short* vrow[4];
    #pragma unroll
    for (int et = 0; et < 4; ++et)
        vrow[et] = Vbase + (long)(et * 16 + l16) * SEQ + quad * 4;

    int s0 = wv * 64;
    if (s0 <= q_hi) {
        // preload iter 0: K frags (8 x 16B), V frags (16 x 8B)
        bf16x8 ck[4][2];
        bf16x4 cv[4][4];
        #pragma unroll
        for (int kh = 0; kh < 4; ++kh) {
            const short* kp = Kbase + (long)(s0 + kh * 16 + l16) * DOUT + quad * 8;
            ck[kh][0] = *(const bf16x8*)(kp);
            ck[kh][1] = *(const bf16x8*)(kp + 32);
        }
        #pragma unroll
        for (int et = 0; et < 4; ++et)
            #pragma unroll
            for (int kh = 0; kh < 4; ++kh)
                cv[et][kh] = *(const bf16x4*)(vrow[et] + s0 + kh * 16);

        for (; s0 <= q_hi; s0 += 256) {
            // ---- scores^T: 64 keys x 16 q ----
            f32x4 sc[4];
            #pragma unroll
            for (int kh = 0; kh < 4; ++kh) {
                sc[kh] = (f32x4){0.f, 0.f, 0.f, 0.f};
                sc[kh] = mfma16(ck[kh][0], qf0, sc[kh]);
                sc[kh] = mfma16(ck[kh][1], qf1, sc[kh]);
            }

            // ---- prefetch next K (clamped to a valid tile) ----
            const int sn = s0 + 256;
            const int sb = (sn <= q_hi) ? sn : s0;
            bf16x8 nk[4][2];
            #pragma unroll
            for (int kh = 0; kh < 4; ++kh) {
                const short* kpn = Kbase + (long)(sb + kh * 16 + l16) * DOUT + quad * 8;
                nk[kh][0] = *(const bf16x8*)(kpn);
                nk[kh][1] = *(const bf16x8*)(kpn + 32);
            }
            __builtin_amdgcn_sched_barrier(0);   // pin K prefetch above softmax

            // ---- causal mask (key <= q) ----
            #pragma unroll
            for (int kh = 0; kh < 4; ++kh)
                #pragma unroll
                for (int r = 0; r < 4; ++r)
                    sc[kh][r] = ((s0 + kh * 16 + quad * 4 + r) <= qg) ? sc[kh][r] : -1e30f;

            // ---- online softmax (base 2), per-lane q ----
            float tm = -1e30f;
            #pragma unroll
            for (int kh = 0; kh < 4; ++kh)
                #pragma unroll
                for (int r = 0; r < 4; ++r) tm = fmaxf(tm, sc[kh][r]);
            tm = fmaxf(tm, __shfl_xor(tm, 16, 64));
            tm = fmaxf(tm, __shfl_xor(tm, 32, 64));
            const float mn = fmaxf(mrow, tm);
            const float alpha = __builtin_amdgcn_exp2f(mrow - mn);
            mrow = mn;
            float p[4][4];
            float rs = 0.f;
            #pragma unroll
            for (int kh = 0; kh < 4; ++kh)
                #pragma unroll
                for (int r = 0; r < 4; ++r) {
                    p[kh][r] = __builtin_amdgcn_exp2f(sc[kh][r] - mn);
                    rs += p[kh][r];
                }
            rs += __shfl_xor(rs, 16, 64);
            rs += __shfl_xor(rs, 32, 64);
            lrow = lrow * alpha + rs;
            #pragma unroll
            for (int e = 0; e < 4; ++e)
                #pragma unroll
                for (int r = 0; r < 4; ++r) acc[e][r] *= alpha;

            // ---- pack P (already in B-frag layout for K=16 MFMA) ----
            union { unsigned u[2]; bf16x4 v; } pf[4];
            #pragma unroll
            for (int kh = 0; kh < 4; ++kh) {
                pf[kh].u[0] = pack_bf2(p[kh][0], p[kh][1]);
                pf[kh].u[1] = pack_bf2(p[kh][2], p[kh][3]);
            }

            // ---- O^T += V^T · P^T ----
            #pragma unroll
            for (int kh = 0; kh < 4; ++kh)
                #pragma unroll
                for (int et = 0; et < 4; ++et)
                    acc[et] = mfma16k(cv[et][kh], pf[kh].v, acc[et]);

            // ---- prefetch next V (after cv consumed; covers next softmax) ----
            bf16x4 nv[4][4];
            #pragma unroll
            for (int et = 0; et < 4; ++et)
                #pragma unroll
                for (int kh = 0; kh < 4; ++kh)
                    nv[et][kh] = *(const bf16x4*)(vrow[et] + sb + kh * 16);
            __builtin_amdgcn_sched_barrier(0);   // pin V prefetch above next iter

            #pragma unroll
            for (int kh = 0; kh < 4; ++kh) { ck[kh][0] = nk[kh][0]; ck[kh][1] = nk[kh][1]; }
            #pragma unroll
            for (int et = 0; et < 4; ++et)
                #pragma unroll
                for (int kh = 0; kh < 4; ++kh) cv[et][kh] = nv[et][kh];
        }
    }

    // ---- publish per-wave partials (per lane: one q-row = l16) ----
    if (quad == 0) { s_m[wv][l16] = mrow; s_l[wv][l16] = lrow; }
    #pragma unroll
    for (int et = 0; et < 4; ++et)
        #pragma unroll
        for (int r = 0; r < 4; ++r)
            s_acc[wv][l16][et * 16 + quad * 4 + r] = acc[et][r];
    __syncthreads();

    // ---- merge 4 wave-partials; thread = (row-group, col) ----
    const int col = tid & 63;
    const int r0  = (tid >> 6) * 4;
    float* outp = Out + ((long)b * SEQ + q0) * DOUT;
    #pragma unroll
    for (int r = 0; r < 4; ++r) {
        const int row = r0 + r;
        const float m0 = s_m[0][row], m1 = s_m[1][row];
        const float m2 = s_m[2][row], m3 = s_m[3][row];
        const float mM = fmaxf(fmaxf(m0, m1), fmaxf(m2, m3));
        const float a0 = __builtin_amdgcn_exp2f(m0 - mM);
        const float a1 = __builtin_amdgcn_exp2f(m1 - mM);
        const float a2 = __builtin_amdgcn_exp2f(m2 - mM);
        const float a3 = __builtin_amdgcn_exp2f(m3 - mM);
        const float li = a0 * s_l[0][row] + a1 * s_l[1][row]
                       + a2 * s_l[2][row] + a3 * s_l[3][row];
        const float o  = a0 * s_acc[0][row][col] + a1 * s_acc[1][row][col]
                       + a2 * s_acc[2][row][col] + a3 * s_acc[3][row][col];
        outp[row * DOUT + col] = o / li;
    }
}

extern "C" void kernel_launch(void* const* d_in, const int* in_sizes, int n_in,
                              void* d_out, int out_size, void* d_ws, size_t ws_size,
                              hipStream_t stream) {
    const float* key_in   = (const float*)d_in[0];
    const float* value_in = (const float*)d_in[1];
    const float* query_in = (const float*)d_in[2];
    const float* Wq = (const float*)d_in[3];
    const float* Wk = (const float*)d_in[4];
    const float* Wv = (const float*)d_in[5];
    float* out = (float*)d_out;

    short* Qb = (short*)d_ws;                          // 2 MB bf16 [B][S][64]  (pre-scaled)
    short* Kb = Qb + (long)BATCH * SEQ * DOUT;         // 2 MB bf16 [B][S][64]
    short* Vt = Kb + (long)BATCH * SEQ * DOUT;         // 2 MB bf16 [B][64][S]
    short* Wt = Vt + (long)BATCH * SEQ * DOUT;         // 192 KB bf16 [3][64][512]

    dim3 wgrid((DOUT * DIN) / 256, 3);
    wconv_kernel<<<wgrid, 256, 0, stream>>>(Wq, Wk, Wv, Wt);

    dim3 pgrid(BATCH * SEQ / 64, 3);
    proj_kernel<<<pgrid, 256, 0, stream>>>(query_in, key_in, value_in,
                                           Wt, Qb, Kb, Vt);

    flash_kernel<<<dim3(SEQ / 16 * BATCH), 256, 0, stream>>>(Qb, Kb, Vt, out);
}

// Round 8
// 181.728 us; speedup vs baseline: 1.3945x; 1.3945x over previous
//
#include <hip/hip_runtime.h>
#include <hip/hip_bf16.h>

#define BATCH 4
#define SEQ   4096
#define DIN   512
#define DOUT  64

typedef __attribute__((ext_vector_type(4))) float f32x4;
typedef __attribute__((ext_vector_type(8))) short bf16x8;   // 8 bf16 = 16B
typedef __attribute__((ext_vector_type(4))) short bf16x4;   // 4 bf16 = 8B

__device__ __forceinline__ f32x4 mfma16(bf16x8 a, bf16x8 b, f32x4 c) {
    return __builtin_amdgcn_mfma_f32_16x16x32_bf16(a, b, c, 0, 0, 0);
}
// K=16 variant: A[m][k]: m=lane&15, k=quad*4+j ; B[k][n]: n=lane&15, k=quad*4+j
__device__ __forceinline__ f32x4 mfma16k(bf16x4 a, bf16x4 b, f32x4 c) {
    return __builtin_amdgcn_mfma_f32_16x16x16bf16_1k(a, b, c, 0, 0, 0);
}

// fp32 -> bf16 round-to-nearest-even (finite inputs only)
__device__ __forceinline__ short f2bf(float f) {
    union { float f; unsigned u; } x; x.f = f;
    unsigned r = x.u + 0x7FFFu + ((x.u >> 16) & 1u);
    return (short)(r >> 16);
}

// pack two fp32 into bf16x2 (truncation) in ONE v_perm_b32
__device__ __forceinline__ unsigned pack_bf2(float lo, float hi) {
    union { float f; unsigned u; } a, b; a.f = lo; b.f = hi;
    return __builtin_amdgcn_perm(b.u, a.u, 0x07060302u);
}

// async global->LDS DMA, 16B/lane; LDS dest = wave-uniform base + lane*16.
// R7 lesson: NEVER use the imm-offset arg (ambiguous whether it shifts the
// global or the LDS address -> unwritten LDS slots -> junk bf16 -> NaN).
// All offsets are folded into the pointers; offset arg is always 0.
__device__ __forceinline__ void dma16(const void* g, void* l) {
    __builtin_amdgcn_global_load_lds(
        (const __attribute__((address_space(1))) void*)g,
        (__attribute__((address_space(3))) void*)l, 16, 0, 0);
}

// Q pre-scale: 1/sqrt(64) * log2(e)  (softmax done in base 2)
#define QSCALE 0.1803368801111204f

// ---------------------------------------------------------------------------
// W convert+transpose: W[512][64] fp32 -> Wt[64][512] bf16 (coalesced reads).
// ---------------------------------------------------------------------------
__global__ __launch_bounds__(256) void wconv_kernel(
    const float* __restrict__ Wq, const float* __restrict__ Wk,
    const float* __restrict__ Wv, short* __restrict__ Wt)
{
    const int m = blockIdx.y;
    const float* W = (m == 0) ? Wq : (m == 1) ? Wk : Wv;
    const int idx = blockIdx.x * 256 + threadIdx.x;   // 0..32767
    const int k = idx >> 6;
    const int n = idx & 63;
    Wt[m * (DOUT * DIN) + n * DIN + k] = f2bf(W[idx]);
}

// ---------------------------------------------------------------------------
// QKV projection, m97-style global_load_lds staging, double-buffered BK=64.
// LDS tiles in FRAGMENT ORDER (lane's frag at lane*16): ds_read_b128
// conflict-free; DMA global side 16B-contiguous per lane.
// Block: 64 rows (4 waves x 16). LDS 2 x (16KB X + 8KB W) = 48KB, 3 blk/CU.
// m<2 : C = X*W -> Qb/Kb row-major (Q pre-scaled); m==2: swapped operands ->
// Vt[e][s] transposed, 32B-contiguous stores.
// ---------------------------------------------------------------------------
__global__ __launch_bounds__(256) void proj_kernel(
    const float* __restrict__ Xq, const float* __restrict__ Xk, const float* __restrict__ Xv,
    const short* __restrict__ Wt,
    short* __restrict__ Qb, short* __restrict__ Kb, short* __restrict__ Vt)
{
    __shared__ __align__(16) char smem[2][24576];   // [buf][ X 16KB | W 8KB ]

    const int m = blockIdx.y;
    const float* X  = (m == 0) ? Xq : (m == 1) ? Xk : Xv;
    const short* Wm = Wt + m * (DOUT * DIN);

    const int tid  = threadIdx.x;
    const int wv   = tid >> 6;
    const int lane = tid & 63;
    const int quad = lane >> 4;
    const int l16  = lane & 15;
    const long waveRow = (long)blockIdx.x * 64 + wv * 16;

    // per-lane DMA sources (advance by 64 k-elements per BK step)
    const float* xg = X  + (waveRow + l16) * DIN + quad * 8;
    const short* wg = Wm + (long)(wv * 16 + l16) * DIN + quad * 8;

    f32x4 acc[4];
    #pragma unroll
    for (int e = 0; e < 4; ++e) acc[e] = (f32x4){0.f, 0.f, 0.f, 0.f};

    // X slots (per wave, 4KB): slot (c2*2+h)*1024 holds X[l16][c2*32+quad*8+h*4 ..+3]
    // W slots (per wave, 2KB): slot h*1024 holds Wt[wv*16+l16][h*32+quad*8 ..+7]
#define STAGE_PROJ(B) do {                                   \
        char* xb_ = &smem[(B)][0] + wv * 4096;               \
        char* wb_ = &smem[(B)][0] + 16384 + wv * 2048;       \
        dma16(xg,      xb_);                                 \
        dma16(xg + 4,  xb_ + 1024);                          \
        dma16(xg + 32, xb_ + 2048);                          \
        dma16(xg + 36, xb_ + 3072);                          \
        dma16(wg,      wb_);                                 \
        dma16(wg + 32, wb_ + 1024);                          \
    } while (0)

    STAGE_PROJ(0);
    xg += 64; wg += 64;
    __syncthreads();

    for (int kt = 0; kt < 8; ++kt) {
        const int cur = kt & 1;
        if (kt < 7) {
            if (cur) { STAGE_PROJ(0); } else { STAGE_PROJ(1); }
            xg += 64; wg += 64;
        }
        const char* xb = &smem[cur][0] + wv * 4096;
        const char* wb = &smem[cur][0] + 16384;
        #pragma unroll
        for (int c2 = 0; c2 < 2; ++c2) {
            float4 xa = *(const float4*)(xb + c2 * 2048 + lane * 16);
            float4 xc = *(const float4*)(xb + c2 * 2048 + 1024 + lane * 16);
            bf16x8 af;
            af[0] = f2bf(xa.x); af[1] = f2bf(xa.y); af[2] = f2bf(xa.z); af[3] = f2bf(xa.w);
            af[4] = f2bf(xc.x); af[5] = f2bf(xc.y); af[6] = f2bf(xc.z); af[7] = f2bf(xc.w);
            #pragma unroll
            for (int e = 0; e < 4; ++e) {
                bf16x8 bf = *(const bf16x8*)(wb + (e * 2 + c2) * 1024 + lane * 16);
                if (m < 2) acc[e] = mfma16(af, bf, acc[e]);
                else       acc[e] = mfma16(bf, af, acc[e]);
            }
        }
        __syncthreads();
    }
#undef STAGE_PROJ

    if (m < 2) {
        short* O = (m == 0) ? Qb : Kb;
        const float sc = (m == 0) ? QSCALE : 1.0f;
        #pragma unroll
        for (int e = 0; e < 4; ++e)
            #pragma unroll
            for (int r = 0; r < 4; ++r)
                O[(waveRow + quad * 4 + r) * DOUT + e * 16 + l16] = f2bf(acc[e][r] * sc);
    } else {
        const long b = waveRow >> 12;
        const long s = waveRow & (SEQ - 1);
        #pragma unroll
        for (int e = 0; e < 4; ++e)
            #pragma unroll
            for (int r = 0; r < 4; ++r)
                Vt[(b * DOUT + e * 16 + quad * 4 + r) * SEQ + s + l16] = f2bf(acc[e][r]);
    }
}

// ---------------------------------------------------------------------------
// Causal flash attention: R5's verified per-wave math, KV DMA-staged via LDS.
// Block = 16-row q-tile, 4 waves kv-split (wave w: keys r*256 + w*64..+63).
// K tile: fragment order, 8 slots of 1KB. V tile: granule-swizzled
// (slot j holds 16B granule c = j ^ (e&7)) -> ds_read_b64 <=2-way conflicts.
// LDS: K 32KB + V 32KB = 64KB single buffer -> 2 blocks/CU. Merge arrays
// alias the KV buffer after the loop.
// ---------------------------------------------------------------------------
__global__ __launch_bounds__(256) void flash_kernel(
    const short* __restrict__ Qb, const short* __restrict__ Kb,
    const short* __restrict__ Vt, float* __restrict__ Out)
{
    __shared__ __align__(16) char smem[65536];   // K: 0..32K, V: 32K..64K

    const int i    = blockIdx.x;
    const int b    = (i & 7) >> 1;                       // batch -> XCD pair
    const int qt   = 255 - (((i >> 3) << 1) | (i & 1));  // heavy tiles first
    const int tid  = threadIdx.x;
    const int wv   = tid >> 6;
    const int lane = tid & 63;
    const int quad = lane >> 4;
    const int l16  = lane & 15;
    const int q0   = qt * 16;

    // Q as B-frag: B[k=d][n=q]
    const short* Qp = Qb + ((long)b * SEQ + q0 + l16) * DOUT + quad * 8;
    bf16x8 qf0 = *(const bf16x8*)(Qp);
    bf16x8 qf1 = *(const bf16x8*)(Qp + 32);

    const short* Kbase  = Kb + (long)b * SEQ * DOUT;
    const short* VbaseG = Vt + (long)b * DOUT * SEQ;

    // per-lane DMA sources (advance per round)
    const short* gk = Kbase + (long)(wv * 64 + l16) * DOUT + quad * 8;
    // V: lane covers row e = v*8 + (lane>>3); chunk-slot j = lane&7 holds
    // global granule c = j ^ ((lane>>3)&7)
    const short* gv = VbaseG + (long)(lane >> 3) * SEQ + wv * 64
                    + (((lane & 7) ^ ((lane >> 3) & 7)) * 8);

    char* ks = smem + wv * 8192;            // K slots (kh*2+half)*1024
    char* vs = smem + 32768 + wv * 8192;    // V slots v*1024 (rows v*8..v*8+7)

    f32x4 acc[4];
    #pragma unroll
    for (int e = 0; e < 4; ++e) acc[e] = (f32x4){0.f, 0.f, 0.f, 0.f};
    float mrow = -1e30f, lrow = 0.f;

    const int q_hi  = q0 + 15;
    const int qg    = q0 + l16;
    const int wbase = wv * 64;
    const int R     = q0 / 256 + 1;
    const int f8    = (l16 & 7) << 1;

    for (int r = 0; r < R; ++r) {
        const int kv0 = r * 256;
        const bool act = (kv0 + wbase) <= q_hi;

        if (act) {
            // K tile: slots (kh*2+h)*1024 <- K[wbase + kh*16 + l16][h*32 + quad*8..]
            dma16(gk,                  ks);
            dma16(gk + 32,             ks + 1024);
            dma16(gk + 16 * DOUT,      ks + 2048);
            dma16(gk + 16 * DOUT + 32, ks + 3072);
            dma16(gk + 32 * DOUT,      ks + 4096);
            dma16(gk + 32 * DOUT + 32, ks + 5120);
            dma16(gk + 48 * DOUT,      ks + 6144);
            dma16(gk + 48 * DOUT + 32, ks + 7168);
            // V tile: 8 row-blocks of 8 e-rows
            dma16(gv,           vs);
            dma16(gv +  8 * SEQ, vs + 1024);
            dma16(gv + 16 * SEQ, vs + 2048);
            dma16(gv + 24 * SEQ, vs + 3072);
            dma16(gv + 32 * SEQ, vs + 4096);
            dma16(gv + 40 * SEQ, vs + 5120);
            dma16(gv + 48 * SEQ, vs + 6144);
            dma16(gv + 56 * SEQ, vs + 7168);
        }
        __syncthreads();   // drain DMA; publish tiles

        if (act) {
            // ---- scores^T: 64 keys x 16 q ----
            f32x4 sc[4];
            #pragma unroll
            for (int kh = 0; kh < 4; ++kh) {
                bf16x8 k0 = *(const bf16x8*)(ks + (kh * 2 + 0) * 1024 + lane * 16);
                bf16x8 k1 = *(const bf16x8*)(ks + (kh * 2 + 1) * 1024 + lane * 16);
                f32x4 z = (f32x4){0.f, 0.f, 0.f, 0.f};
                z = mfma16(k0, qf0, z);
                z = mfma16(k1, qf1, z);
                sc[kh] = z;
            }

            // ---- causal mask (key <= q) ----
            #pragma unroll
            for (int kh = 0; kh < 4; ++kh)
                #pragma unroll
                for (int rr = 0; rr < 4; ++rr)
                    sc[kh][rr] = ((kv0 + wbase + kh * 16 + quad * 4 + rr) <= qg)
                               ? sc[kh][rr] : -1e30f;

            // ---- online softmax (base 2), per-lane q ----
            float tm = -1e30f;
            #pragma unroll
            for (int kh = 0; kh < 4; ++kh)
                #pragma unroll
                for (int rr = 0; rr < 4; ++rr) tm = fmaxf(tm, sc[kh][rr]);
            tm = fmaxf(tm, __shfl_xor(tm, 16, 64));
            tm = fmaxf(tm, __shfl_xor(tm, 32, 64));
            const float mn = fmaxf(mrow, tm);
            const float alpha = __builtin_amdgcn_exp2f(mrow - mn);
            mrow = mn;
            float p[4][4];
            float rs = 0.f;
            #pragma unroll
            for (int kh = 0; kh < 4; ++kh)
                #pragma unroll
                for (int rr = 0; rr < 4; ++rr) {
                    p[kh][rr] = __builtin_amdgcn_exp2f(sc[kh][rr] - mn);
                    rs += p[kh][rr];
                }
            rs += __shfl_xor(rs, 16, 64);
            rs += __shfl_xor(rs, 32, 64);
            lrow = lrow * alpha + rs;
            #pragma unroll
            for (int e = 0; e < 4; ++e)
                #pragma unroll
                for (int rr = 0; rr < 4; ++rr) acc[e][rr] *= alpha;

            // ---- pack P (already in B-frag layout for K=16 MFMA) ----
            union { unsigned u[2]; bf16x4 v; } pf[4];
            #pragma unroll
            for (int kh = 0; kh < 4; ++kh) {
                pf[kh].u[0] = pack_bf2(p[kh][0], p[kh][1]);
                pf[kh].u[1] = pack_bf2(p[kh][2], p[kh][3]);
            }

            // ---- O^T += V^T * P^T  (V from LDS, granule-swizzled) ----
            #pragma unroll
            for (int kh = 0; kh < 4; ++kh) {
                #pragma unroll
                for (int et = 0; et < 4; ++et) {
                    const int e = et * 16 + l16;
                    const int g = kh * 4 + quad;
                    bf16x4 cv = *(const bf16x4*)(vs + e * 128 + ((g ^ f8) * 8));
                    acc[et] = mfma16k(cv, pf[kh].v, acc[et]);
                }
            }
        }
        __syncthreads();   // all reads done before next round's stage

        gk += 256 * DOUT;
        gv += 256;
    }

    // ---- epilogue: merge arrays alias the (dead) KV buffer ----
    float* s_m   = (float*)smem;            // [4][16]
    float* s_l   = (float*)(smem + 256);    // [4][16]
    float* s_acc = (float*)(smem + 512);    // [4][16][65]

    if (quad == 0) { s_m[wv * 16 + l16] = mrow; s_l[wv * 16 + l16] = lrow; }
    #pragma unroll
    for (int et = 0; et < 4; ++et)
        #pragma unroll
        for (int rr = 0; rr < 4; ++rr)
            s_acc[(wv * 16 + l16) * 65 + et * 16 + quad * 4 + rr] = acc[et][rr];
    __syncthreads();

    const int col = tid & 63;
    const int r0  = (tid >> 6) * 4;
    float* outp = Out + ((long)b * SEQ + q0) * DOUT;
    #pragma unroll
    for (int rr = 0; rr < 4; ++rr) {
        const int row = r0 + rr;
        const float m0 = s_m[row], m1 = s_m[16 + row];
        const float m2 = s_m[32 + row], m3 = s_m[48 + row];
        const float mM = fmaxf(fmaxf(m0, m1), fmaxf(m2, m3));
        const float a0 = __builtin_amdgcn_exp2f(m0 - mM);
        const float a1 = __builtin_amdgcn_exp2f(m1 - mM);
        const float a2 = __builtin_amdgcn_exp2f(m2 - mM);
        const float a3 = __builtin_amdgcn_exp2f(m3 - mM);
        const float li = a0 * s_l[row] + a1 * s_l[16 + row]
                       + a2 * s_l[32 + row] + a3 * s_l[48 + row];
        const float o  = a0 * s_acc[(0 * 16 + row) * 65 + col]
                       + a1 * s_acc[(1 * 16 + row) * 65 + col]
                       + a2 * s_acc[(2 * 16 + row) * 65 + col]
                       + a3 * s_acc[(3 * 16 + row) * 65 + col];
        outp[row * DOUT + col] = o / li;
    }
}

extern "C" void kernel_launch(void* const* d_in, const int* in_sizes, int n_in,
                              void* d_out, int out_size, void* d_ws, size_t ws_size,
                              hipStream_t stream) {
    const float* key_in   = (const float*)d_in[0];
    const float* value_in = (const float*)d_in[1];
    const float* query_in = (const float*)d_in[2];
    const float* Wq = (const float*)d_in[3];
    const float* Wk = (const float*)d_in[4];
    const float* Wv = (const float*)d_in[5];
    float* out = (float*)d_out;

    short* Qb = (short*)d_ws;                          // 2 MB bf16 [B][S][64]  (pre-scaled)
    short* Kb = Qb + (long)BATCH * SEQ * DOUT;         // 2 MB bf16 [B][S][64]
    short* Vt = Kb + (long)BATCH * SEQ * DOUT;         // 2 MB bf16 [B][64][S]
    short* Wt = Vt + (long)BATCH * SEQ * DOUT;         // 192 KB bf16 [3][64][512]

    dim3 wgrid((DOUT * DIN) / 256, 3);
    wconv_kernel<<<wgrid, 256, 0, stream>>>(Wq, Wk, Wv, Wt);

    dim3 pgrid(BATCH * SEQ / 64, 3);
    proj_kernel<<<pgrid, 256, 0, stream>>>(query_in, key_in, value_in,
                                           Wt, Qb, Kb, Vt);

    flash_kernel<<<dim3(SEQ / 16 * BATCH), 256, 0, stream>>>(Qb, Kb, Vt, out);
}

// Round 9
// 178.040 us; speedup vs baseline: 1.4233x; 1.0207x over previous
//
#include <hip/hip_runtime.h>
#include <hip/hip_bf16.h>

#define BATCH 4
#define SEQ   4096
#define DIN   512
#define DOUT  64

typedef __attribute__((ext_vector_type(4))) float f32x4;
typedef __attribute__((ext_vector_type(8))) short bf16x8;   // 8 bf16 = 16B
typedef __attribute__((ext_vector_type(4))) short bf16x4;   // 4 bf16 = 8B

__device__ __forceinline__ f32x4 mfma16(bf16x8 a, bf16x8 b, f32x4 c) {
    return __builtin_amdgcn_mfma_f32_16x16x32_bf16(a, b, c, 0, 0, 0);
}
// K=16 variant: A[m][k]: m=lane&15, k=quad*4+j ; B[k][n]: n=lane&15, k=quad*4+j
__device__ __forceinline__ f32x4 mfma16k(bf16x4 a, bf16x4 b, f32x4 c) {
    return __builtin_amdgcn_mfma_f32_16x16x16bf16_1k(a, b, c, 0, 0, 0);
}

// fp32 -> bf16 round-to-nearest-even (finite inputs only)
__device__ __forceinline__ short f2bf(float f) {
    union { float f; unsigned u; } x; x.f = f;
    unsigned r = x.u + 0x7FFFu + ((x.u >> 16) & 1u);
    return (short)(r >> 16);
}

// pack two fp32 into bf16x2 (truncation) in ONE v_perm_b32
__device__ __forceinline__ unsigned pack_bf2(float lo, float hi) {
    union { float f; unsigned u; } a, b; a.f = lo; b.f = hi;
    return __builtin_amdgcn_perm(b.u, a.u, 0x07060302u);
}

// async global->LDS DMA, 16B/lane; LDS dest = wave-uniform base + lane*16.
// R7 lesson: never use the imm-offset arg; fold all offsets into pointers.
__device__ __forceinline__ void dma16(const void* g, void* l) {
    __builtin_amdgcn_global_load_lds(
        (const __attribute__((address_space(1))) void*)g,
        (__attribute__((address_space(3))) void*)l, 16, 0, 0);
}

// Q pre-scale: 1/sqrt(64) * log2(e)  (softmax done in base 2)
#define QSCALE 0.1803368801111204f

// ---------------------------------------------------------------------------
// W convert+transpose: W[512][64] fp32 -> Wt[64][512] bf16 (coalesced reads).
// ---------------------------------------------------------------------------
__global__ __launch_bounds__(256) void wconv_kernel(
    const float* __restrict__ Wq, const float* __restrict__ Wk,
    const float* __restrict__ Wv, short* __restrict__ Wt)
{
    const int m = blockIdx.y;
    const float* W = (m == 0) ? Wq : (m == 1) ? Wk : Wv;
    const int idx = blockIdx.x * 256 + threadIdx.x;   // 0..32767
    const int k = idx >> 6;
    const int n = idx & 63;
    Wt[m * (DOUT * DIN) + n * DIN + k] = f2bf(W[idx]);
}

// ---------------------------------------------------------------------------
// QKV projection (unchanged from R8 — passed): global_load_lds staging,
// double-buffered BK=64, fragment-order LDS, 48KB, 3 blk/CU.
// ---------------------------------------------------------------------------
__global__ __launch_bounds__(256) void proj_kernel(
    const float* __restrict__ Xq, const float* __restrict__ Xk, const float* __restrict__ Xv,
    const short* __restrict__ Wt,
    short* __restrict__ Qb, short* __restrict__ Kb, short* __restrict__ Vt)
{
    __shared__ __align__(16) char smem[2][24576];   // [buf][ X 16KB | W 8KB ]

    const int m = blockIdx.y;
    const float* X  = (m == 0) ? Xq : (m == 1) ? Xk : Xv;
    const short* Wm = Wt + m * (DOUT * DIN);

    const int tid  = threadIdx.x;
    const int wv   = tid >> 6;
    const int lane = tid & 63;
    const int quad = lane >> 4;
    const int l16  = lane & 15;
    const long waveRow = (long)blockIdx.x * 64 + wv * 16;

    const float* xg = X  + (waveRow + l16) * DIN + quad * 8;
    const short* wg = Wm + (long)(wv * 16 + l16) * DIN + quad * 8;

    f32x4 acc[4];
    #pragma unroll
    for (int e = 0; e < 4; ++e) acc[e] = (f32x4){0.f, 0.f, 0.f, 0.f};

#define STAGE_PROJ(B) do {                                   \
        char* xb_ = &smem[(B)][0] + wv * 4096;               \
        char* wb_ = &smem[(B)][0] + 16384 + wv * 2048;       \
        dma16(xg,      xb_);                                 \
        dma16(xg + 4,  xb_ + 1024);                          \
        dma16(xg + 32, xb_ + 2048);                          \
        dma16(xg + 36, xb_ + 3072);                          \
        dma16(wg,      wb_);                                 \
        dma16(wg + 32, wb_ + 1024);                          \
    } while (0)

    STAGE_PROJ(0);
    xg += 64; wg += 64;
    __syncthreads();

    for (int kt = 0; kt < 8; ++kt) {
        const int cur = kt & 1;
        if (kt < 7) {
            if (cur) { STAGE_PROJ(0); } else { STAGE_PROJ(1); }
            xg += 64; wg += 64;
        }
        const char* xb = &smem[cur][0] + wv * 4096;
        const char* wb = &smem[cur][0] + 16384;
        #pragma unroll
        for (int c2 = 0; c2 < 2; ++c2) {
            float4 xa = *(const float4*)(xb + c2 * 2048 + lane * 16);
            float4 xc = *(const float4*)(xb + c2 * 2048 + 1024 + lane * 16);
            bf16x8 af;
            af[0] = f2bf(xa.x); af[1] = f2bf(xa.y); af[2] = f2bf(xa.z); af[3] = f2bf(xa.w);
            af[4] = f2bf(xc.x); af[5] = f2bf(xc.y); af[6] = f2bf(xc.z); af[7] = f2bf(xc.w);
            #pragma unroll
            for (int e = 0; e < 4; ++e) {
                bf16x8 bf = *(const bf16x8*)(wb + (e * 2 + c2) * 1024 + lane * 16);
                if (m < 2) acc[e] = mfma16(af, bf, acc[e]);
                else       acc[e] = mfma16(bf, af, acc[e]);
            }
        }
        __syncthreads();
    }
#undef STAGE_PROJ

    if (m < 2) {
        short* O = (m == 0) ? Qb : Kb;
        const float sc = (m == 0) ? QSCALE : 1.0f;
        #pragma unroll
        for (int e = 0; e < 4; ++e)
            #pragma unroll
            for (int r = 0; r < 4; ++r)
                O[(waveRow + quad * 4 + r) * DOUT + e * 16 + l16] = f2bf(acc[e][r] * sc);
    } else {
        const long b = waveRow >> 12;
        const long s = waveRow & (SEQ - 1);
        #pragma unroll
        for (int e = 0; e < 4; ++e)
            #pragma unroll
            for (int r = 0; r < 4; ++r)
                Vt[(b * DOUT + e * 16 + quad * 4 + r) * SEQ + s + l16] = f2bf(acc[e][r]);
    }
}

// ---------------------------------------------------------------------------
// Causal flash attention v2: KV SHARED across the block + double-buffered
// single-sync rounds (R8 post-mortem: 557MB restaging + exposed DMA drain).
// Block = 32 q-rows: 4 waves = (wq in {0,1} q-tile) x (wk in {0,1} kv-half).
// Round = 128 keys: K 16KB (16 fragment-order slots) + V 16KB (rows e*256B,
// 16B granule c stored at slot c ^ (e&15) -> bank-uniform b64 reads).
// Loop: stage(r+1 into buf^1); compute(buf); sync  -- DMA flies under compute.
// 2x32KB LDS -> 2 blocks/CU. 2-way merge epilogue (wk pairs) aliases LDS.
// Math/fragment layouts byte-identical to R8 (verified).
// ---------------------------------------------------------------------------
__global__ __launch_bounds__(256) void flash_kernel(
    const short* __restrict__ Qb, const short* __restrict__ Kb,
    const short* __restrict__ Vt, float* __restrict__ Out)
{
    __shared__ __align__(16) char smem[2][32768];   // [buf][ K 16KB | V 16KB ]

    const int i    = blockIdx.x;                        // 512 blocks
    const int b    = (i & 7) >> 1;                      // batch -> XCD pair
    const int t    = 127 - (((i >> 3) << 1) | (i & 1)); // heavy tiles first
    const int tid  = threadIdx.x;
    const int wv   = tid >> 6;
    const int lane = tid & 63;
    const int quad = lane >> 4;
    const int l16  = lane & 15;
    const int wq   = wv >> 1;     // which q-tile
    const int wk   = wv & 1;      // which kv-half of the round
    const int q0w  = t * 32 + wq * 16;

    // Q as B-frag: B[k=d][n=q]
    const short* Qp = Qb + ((long)b * SEQ + q0w + l16) * DOUT + quad * 8;
    bf16x8 qf0 = *(const bf16x8*)(Qp);
    bf16x8 qf1 = *(const bf16x8*)(Qp + 32);

    const short* Kbase  = Kb + (long)b * SEQ * DOUT;
    const short* VbaseG = Vt + (long)b * DOUT * SEQ;

    // K DMA source: wave wv stages kh = wv and wv+4 (rows kv0+kh*16+l16)
    const short* gk = Kbase + (long)(wv * 16 + l16) * DOUT + quad * 8;
    // V DMA source: wave wv stages rows 4wv+16k+(lane>>4); granule swizzle
    const int erow = 4 * wv + (lane >> 4);
    const int cgr  = (lane & 15) ^ (erow & 15);
    const short* gv = VbaseG + (long)erow * SEQ + cgr * 8;

    f32x4 acc[4];
    #pragma unroll
    for (int e = 0; e < 4; ++e) acc[e] = (f32x4){0.f, 0.f, 0.f, 0.f};
    float mrow = -1e30f, lrow = 0.f;

    const int q_hi   = q0w + 15;
    const int qg     = q0w + l16;
    const int wfirst = wk * 64;        // wave's first key within a round
    const int R      = t / 4 + 1;      // 128-key rounds

#define STAGE_KV(B, KV0) do {                                         \
        char* kb_ = &smem[(B)][0];                                    \
        char* vb_ = &smem[(B)][0] + 16384;                            \
        const short* gkp_ = gk + (long)(KV0) * DOUT;                  \
        dma16(gkp_,                  kb_ + (2 * wv) * 1024);          \
        dma16(gkp_ + 32,             kb_ + (2 * wv + 1) * 1024);      \
        dma16(gkp_ + 64 * DOUT,      kb_ + (2 * wv + 8) * 1024);      \
        dma16(gkp_ + 64 * DOUT + 32, kb_ + (2 * wv + 9) * 1024);      \
        const short* gvp_ = gv + (KV0);                               \
        dma16(gvp_,            vb_ + (wv)      * 1024);               \
        dma16(gvp_ + 16 * SEQ, vb_ + (wv + 4)  * 1024);               \
        dma16(gvp_ + 32 * SEQ, vb_ + (wv + 8)  * 1024);               \
        dma16(gvp_ + 48 * SEQ, vb_ + (wv + 12) * 1024);               \
    } while (0)

    STAGE_KV(0, 0);
    __syncthreads();

    for (int r = 0; r < R; ++r) {
        const int kv0 = r * 128;
        const int cur = r & 1;
        if (r + 1 < R) STAGE_KV(cur ^ 1, kv0 + 128);

        if ((kv0 + wfirst) <= q_hi) {
            const char* kb = &smem[cur][0];
            const char* vb = &smem[cur][0] + 16384;

            // ---- scores^T: 64 keys (this wave's half) x 16 q ----
            f32x4 sc[4];
            #pragma unroll
            for (int kh = 0; kh < 4; ++kh) {
                const int slot = (wk * 4 + kh) * 2;
                bf16x8 k0 = *(const bf16x8*)(kb + slot * 1024 + lane * 16);
                bf16x8 k1 = *(const bf16x8*)(kb + (slot + 1) * 1024 + lane * 16);
                f32x4 z = (f32x4){0.f, 0.f, 0.f, 0.f};
                z = mfma16(k0, qf0, z);
                z = mfma16(k1, qf1, z);
                sc[kh] = z;
            }

            // ---- causal mask (key <= q) ----
            #pragma unroll
            for (int kh = 0; kh < 4; ++kh)
                #pragma unroll
                for (int rr = 0; rr < 4; ++rr)
                    sc[kh][rr] = ((kv0 + wfirst + kh * 16 + quad * 4 + rr) <= qg)
                               ? sc[kh][rr] : -1e30f;

            // ---- online softmax (base 2), per-lane q ----
            float tm = -1e30f;
            #pragma unroll
            for (int kh = 0; kh < 4; ++kh)
                #pragma unroll
                for (int rr = 0; rr < 4; ++rr) tm = fmaxf(tm, sc[kh][rr]);
            tm = fmaxf(tm, __shfl_xor(tm, 16, 64));
            tm = fmaxf(tm, __shfl_xor(tm, 32, 64));
            const float mn = fmaxf(mrow, tm);
            const float alpha = __builtin_amdgcn_exp2f(mrow - mn);
            mrow = mn;
            float p[4][4];
            float rs = 0.f;
            #pragma unroll
            for (int kh = 0; kh < 4; ++kh)
                #pragma unroll
                for (int rr = 0; rr < 4; ++rr) {
                    p[kh][rr] = __builtin_amdgcn_exp2f(sc[kh][rr] - mn);
                    rs += p[kh][rr];
                }
            rs += __shfl_xor(rs, 16, 64);
            rs += __shfl_xor(rs, 32, 64);
            lrow = lrow * alpha + rs;
            #pragma unroll
            for (int e = 0; e < 4; ++e)
                #pragma unroll
                for (int rr = 0; rr < 4; ++rr) acc[e][rr] *= alpha;

            // ---- pack P (already B-frag for K=16 MFMA) ----
            union { unsigned u[2]; bf16x4 v; } pf[4];
            #pragma unroll
            for (int kh = 0; kh < 4; ++kh) {
                pf[kh].u[0] = pack_bf2(p[kh][0], p[kh][1]);
                pf[kh].u[1] = pack_bf2(p[kh][2], p[kh][3]);
            }

            // ---- O^T += V^T * P^T  (V from LDS, 16-granule swizzle) ----
            #pragma unroll
            for (int kh = 0; kh < 4; ++kh) {
                const int gbase = wk * 8 + kh * 2 + (quad >> 1);
                #pragma unroll
                for (int et = 0; et < 4; ++et) {
                    const int e = et * 16 + l16;
                    bf16x4 cv = *(const bf16x4*)(vb + e * 256
                                   + ((gbase ^ (e & 15)) * 16) + (quad & 1) * 8);
                    acc[et] = mfma16k(cv, pf[kh].v, acc[et]);
                }
            }
        }
        __syncthreads();   // publishes next buf; guards WAR on this buf
    }
#undef STAGE_KV

    // ---- epilogue: 2-way merge (wk pairs); arrays alias the KV buffer ----
    float* s_m   = (float*)&smem[0][0];          // [4][16]
    float* s_l   = s_m + 64;                     // [4][16]
    float* s_acc = s_l + 64;                     // [4][16][65]

    if (quad == 0) { s_m[wv * 16 + l16] = mrow; s_l[wv * 16 + l16] = lrow; }
    #pragma unroll
    for (int et = 0; et < 4; ++et)
        #pragma unroll
        for (int rr = 0; rr < 4; ++rr)
            s_acc[(wv * 16 + l16) * 65 + et * 16 + quad * 4 + rr] = acc[et][rr];
    __syncthreads();

    const int col   = tid & 63;
    const int rbase = (tid >> 6) * 8;
    float* outp = Out + ((long)b * SEQ + t * 32) * DOUT;
    #pragma unroll
    for (int k = 0; k < 8; ++k) {
        const int row = rbase + k;               // 0..31
        const int w0  = (row >> 4) * 2;          // wk=0 wave of this q-tile
        const int lr  = row & 15;
        const float m0 = s_m[w0 * 16 + lr], m1 = s_m[(w0 + 1) * 16 + lr];
        const float mM = fmaxf(m0, m1);
        const float a0 = __builtin_amdgcn_exp2f(m0 - mM);
        const float a1 = __builtin_amdgcn_exp2f(m1 - mM);
        const float li = a0 * s_l[w0 * 16 + lr] + a1 * s_l[(w0 + 1) * 16 + lr];
        const float o  = a0 * s_acc[(w0 * 16 + lr) * 65 + col]
                       + a1 * s_acc[((w0 + 1) * 16 + lr) * 65 + col];
        outp[row * DOUT + col] = o / li;
    }
}

extern "C" void kernel_launch(void* const* d_in, const int* in_sizes, int n_in,
                              void* d_out, int out_size, void* d_ws, size_t ws_size,
                              hipStream_t stream) {
    const float* key_in   = (const float*)d_in[0];
    const float* value_in = (const float*)d_in[1];
    const float* query_in = (const float*)d_in[2];
    const float* Wq = (const float*)d_in[3];
    const float* Wk = (const float*)d_in[4];
    const float* Wv = (const float*)d_in[5];
    float* out = (float*)d_out;

    short* Qb = (short*)d_ws;                          // 2 MB bf16 [B][S][64]  (pre-scaled)
    short* Kb = Qb + (long)BATCH * SEQ * DOUT;         // 2 MB bf16 [B][S][64]
    short* Vt = Kb + (long)BATCH * SEQ * DOUT;         // 2 MB bf16 [B][64][S]
    short* Wt = Vt + (long)BATCH * SEQ * DOUT;         // 192 KB bf16 [3][64][512]

    dim3 wgrid((DOUT * DIN) / 256, 3);
    wconv_kernel<<<wgrid, 256, 0, stream>>>(Wq, Wk, Wv, Wt);

    dim3 pgrid(BATCH * SEQ / 64, 3);
    proj_kernel<<<pgrid, 256, 0, stream>>>(query_in, key_in, value_in,
                                           Wt, Qb, Kb, Vt);

    flash_kernel<<<dim3(SEQ / 32 * BATCH), 256, 0, stream>>>(Qb, Kb, Vt, out);
}